// Round 9
// baseline (829.310 us; speedup 1.0000x reference)
//
#include <hip/hip_runtime.h>
#include <hip/hip_bf16.h>

#define HID 2048
#define NH 16
#define HD 128
#define INTER 8192
#define SS 2048

typedef unsigned short u16;
typedef __attribute__((ext_vector_type(8))) short short8;
typedef __attribute__((ext_vector_type(4))) short short4v;
typedef __attribute__((ext_vector_type(4))) float f32x4;

__device__ __forceinline__ float bf2f(u16 u) {
    unsigned v = ((unsigned)u) << 16; float f; __builtin_memcpy(&f, &v, 4); return f;
}
__device__ __forceinline__ u16 f2bf(float f) {
    unsigned u; __builtin_memcpy(&u, &f, 4);
    u = u + 0x7FFFu + ((u >> 16) & 1u);   // RNE
    return (u16)(u >> 16);
}

typedef const __attribute__((address_space(1))) void* gas_t;
typedef __attribute__((address_space(3))) void* las_t;
__device__ __forceinline__ void gll16(const void* g, void* l) {
    __builtin_amdgcn_global_load_lds((gas_t)g, (las_t)l, 16, 0, 0);
}

// VALU-pipe cross-lane via DPP (16-lane-row butterfly).
template <int CTRL>
__device__ __forceinline__ float dppf(float x) {
    union { float f; int i; } u; u.f = x;
    u.i = __builtin_amdgcn_update_dpp(u.i, u.i, CTRL, 0xf, 0xf, false);
    return u.f;
}
__device__ __forceinline__ float rmax16(float x) {
    x = fmaxf(x, dppf<0xB1>(x));
    x = fmaxf(x, dppf<0x4E>(x));
    x = fmaxf(x, dppf<0x141>(x));
    x = fmaxf(x, dppf<0x140>(x));
    return x;
}
__device__ __forceinline__ float rsum16(float x) {
    x = x + dppf<0xB1>(x);
    x = x + dppf<0x4E>(x);
    x = x + dppf<0x141>(x);
    x = x + dppf<0x140>(x);
    return x;
}

// ---------------- elementwise / prep kernels ----------------

__global__ __launch_bounds__(256) void cast_f32_bf16_kernel(
    const float* __restrict__ src, u16* __restrict__ dst, int n8) {
    int gid = blockIdx.x * 256 + threadIdx.x;
    if (gid >= n8) return;
    const float4* s = (const float4*)src + (size_t)gid * 2;
    float4 a = s[0], b = s[1];
    short8 o;
    o[0] = (short)f2bf(a.x); o[1] = (short)f2bf(a.y); o[2] = (short)f2bf(a.z); o[3] = (short)f2bf(a.w);
    o[4] = (short)f2bf(b.x); o[5] = (short)f2bf(b.y); o[6] = (short)f2bf(b.z); o[7] = (short)f2bf(b.w);
    *((short8*)dst + gid) = o;
}

__global__ __launch_bounds__(256) void trig_kernel(float2* __restrict__ cs) {
    int id = blockIdx.x * 256 + threadIdx.x;   // < 2048*64
    int s = id >> 6, d = id & 63;
    float freq = expf(-(float)(2 * d) * (1.0f / (float)HD) * 9.210340371976184f); // ln(10000)
    float ang = (float)s * freq;
    cs[id] = make_float2(cosf(ang), sinf(ang));
}

__global__ __launch_bounds__(256) void ln_kernel(
    const float* __restrict__ X, const float* __restrict__ W, const float* __restrict__ Bv,
    u16* __restrict__ out) {
    const int row = blockIdx.x, tid = threadIdx.x;
    const float* xr = X + (size_t)row * HID;
    float4 v0 = ((const float4*)xr)[tid * 2];
    float4 v1 = ((const float4*)xr)[tid * 2 + 1];
    float e[8] = {v0.x, v0.y, v0.z, v0.w, v1.x, v1.y, v1.z, v1.w};
    float s = 0.f, ss2 = 0.f;
#pragma unroll
    for (int i = 0; i < 8; ++i) { s += e[i]; ss2 += e[i] * e[i]; }
#pragma unroll
    for (int m = 1; m < 64; m <<= 1) { s += __shfl_xor(s, m, 64); ss2 += __shfl_xor(ss2, m, 64); }
    __shared__ float red[8];
    if ((tid & 63) == 0) { red[tid >> 6] = s; red[4 + (tid >> 6)] = ss2; }
    __syncthreads();
    s = red[0] + red[1] + red[2] + red[3];
    ss2 = red[4] + red[5] + red[6] + red[7];
    float mean = s * (1.0f / HID);
    float var = ss2 * (1.0f / HID) - mean * mean;
    float rstd = rsqrtf(var + 1e-5f);
    float4 w0 = ((const float4*)W)[tid * 2], w1 = ((const float4*)W)[tid * 2 + 1];
    float4 b0 = ((const float4*)Bv)[tid * 2], b1 = ((const float4*)Bv)[tid * 2 + 1];
    float wv[8] = {w0.x, w0.y, w0.z, w0.w, w1.x, w1.y, w1.z, w1.w};
    float bv[8] = {b0.x, b0.y, b0.z, b0.w, b1.x, b1.y, b1.z, b1.w};
    short8 o;
#pragma unroll
    for (int i = 0; i < 8; ++i) o[i] = (short)f2bf((e[i] - mean) * rstd * wv[i] + bv[i]);
    *((short8*)(out + (size_t)row * HID) + tid) = o;
}

// RoPE on bf16 input (row stride 6144) with output pre-scale (Q gets log2e/sqrt(D))
__global__ __launch_bounds__(256) void rope_kernel(
    const u16* __restrict__ src, u16* __restrict__ dst, const float2* __restrict__ cs,
    float oscale) {
    int gid = blockIdx.x * 256 + threadIdx.x;   // < 4096*16*64
    int d = gid & 63;
    int rh = gid >> 6;
    int h = rh & (NH - 1);
    int row = rh >> 4;               // b*2048+s
    int s = row & (SS - 1);
    unsigned pair = *(const unsigned*)(src + (size_t)row * 6144 + h * HD + 2 * d);
    float x1 = bf2f((u16)(pair & 0xFFFFu));
    float x2 = bf2f((u16)(pair >> 16));
    float2 t = cs[s * 64 + d];
    u16* q = dst + (size_t)row * HID + h * HD;
    q[d] = f2bf((x1 * t.x - x2 * t.y) * oscale);
    q[64 + d] = f2bf((x1 * t.y + x2 * t.x) * oscale);
}

// ---------------- GEMM 256x128, 3-slot counted-vmcnt + 4-phase interleave ----------------
// Outer schedule identical to the validated race-free r6 form:
//   vmcnt(6|0); s_barrier; stage(t+2); <compute tile t>
// Compute is now 4 lockstep phases: {4 A ds_reads -> prio1 -> 8 MFMA -> prio0 ->
// barrier}; B frags read once in phase 0. Phase barriers only ADD sync (no new
// hazards); they align waves so one wave's MFMA overlaps another's ds_reads (T3).
template <int OUT_BF16, int RESID>
__global__ __launch_bounds__(512, 2) void gemm256(
    const u16* __restrict__ A, const u16* __restrict__ B,
    void* __restrict__ C, const float* __restrict__ resid,
    int ldc, int K, int nx) {
    extern __shared__ u16 dyn[];    // 3 slots x (A 256x64 + B 128x64) u16
    const int tid = threadIdx.x;
    const int lane = tid & 63, wid = tid >> 6;
    const int lrow = lane & 15, lg = lane >> 4;
    const int wm = wid >> 2, wn = wid & 3;

    const int orig = blockIdx.x;
    const int wg = (orig & 7) * ((int)gridDim.x >> 3) + (orig >> 3);
    const int bx = wg % nx, by = wg / nx;
    const int m0 = by * 256, n0 = bx * 128;

    const u16* ga[4]; const u16* gb[2];
    int lA[4], lB[2];
#pragma unroll
    for (int i = 0; i < 4; ++i) {
        int c = tid + 512 * i, r = c >> 3, kc = (c & 7) ^ (r & 7);
        ga[i] = A + (size_t)(m0 + r) * K + kc * 8;
        lA[i] = c * 8;
    }
#pragma unroll
    for (int i = 0; i < 2; ++i) {
        int c = tid + 512 * i, r = c >> 3, kc = (c & 7) ^ (r & 7);
        gb[i] = B + (size_t)(n0 + r) * K + kc * 8;
        lB[i] = 16384 + c * 8;
    }
    const int NT = K >> 6;

    auto stage = [&](int slot) {
        u16* s = dyn + slot * 24576;
#pragma unroll
        for (int i = 0; i < 4; ++i) { gll16(ga[i], s + lA[i]); ga[i] += 64; }
#pragma unroll
        for (int i = 0; i < 2; ++i) { gll16(gb[i], s + lB[i]); gb[i] += 64; }
    };

    stage(0);
    stage(1);

    const int rowAb = (wm * 128 + lrow) * 64;
    const int rowBb = 16384 + (wn * 32 + lrow) * 64;
    const int cOff = (lg ^ (lrow & 7)) * 8;

    f32x4 acc[8][2] = {};
    int slot = 0;
    for (int t = 0; t < NT; ++t) {
        if (t + 1 < NT) asm volatile("s_waitcnt vmcnt(6)" ::: "memory");
        else            asm volatile("s_waitcnt vmcnt(0)" ::: "memory");
        __builtin_amdgcn_s_barrier();
        __builtin_amdgcn_sched_barrier(0);
        if (t + 2 < NT) stage(slot == 0 ? 2 : slot - 1);

        const u16* sb = dyn + slot * 24576;
        short8 bf[2][2];
#pragma unroll
        for (int n = 0; n < 2; ++n) {
            bf[n][0] = *(const short8*)(sb + rowBb + n * 1024 + cOff);
            bf[n][1] = *(const short8*)(sb + rowBb + n * 1024 + (cOff ^ 32));
        }
#pragma unroll
        for (int p = 0; p < 4; ++p) {
            short8 af[2][2];
#pragma unroll
            for (int m = 0; m < 2; ++m) {
                af[m][0] = *(const short8*)(sb + rowAb + (2 * p + m) * 1024 + cOff);
                af[m][1] = *(const short8*)(sb + rowAb + (2 * p + m) * 1024 + (cOff ^ 32));
            }
            __builtin_amdgcn_s_setprio(1);
#pragma unroll
            for (int m = 0; m < 2; ++m)
#pragma unroll
                for (int n = 0; n < 2; ++n) {
                    acc[2 * p + m][n] = __builtin_amdgcn_mfma_f32_16x16x32_bf16(af[m][0], bf[n][0], acc[2 * p + m][n], 0, 0, 0);
                    acc[2 * p + m][n] = __builtin_amdgcn_mfma_f32_16x16x32_bf16(af[m][1], bf[n][1], acc[2 * p + m][n], 0, 0, 0);
                }
            __builtin_amdgcn_s_setprio(0);
            if (p < 3) {
                __builtin_amdgcn_sched_barrier(0);
                __builtin_amdgcn_s_barrier();
            }
        }
        slot = slot == 2 ? 0 : slot + 1;
    }

#pragma unroll
    for (int m = 0; m < 8; ++m)
#pragma unroll
        for (int n = 0; n < 2; ++n)
#pragma unroll
            for (int j = 0; j < 4; ++j) {
                int gm = m0 + wm * 128 + m * 16 + 4 * lg + j;
                int gn = n0 + wn * 32 + n * 16 + lrow;
                float v = acc[m][n][j];
                if (RESID) v += resid[(size_t)gm * ldc + gn];
                if (OUT_BF16) ((u16*)C)[(size_t)gm * ldc + gn] = f2bf(v);
                else ((float*)C)[(size_t)gm * ldc + gn] = v;
            }
}

// ---- gate/up GEMM + SiLU, same 3-slot schedule + 4-phase interleave ----
__global__ __launch_bounds__(512, 2) void gemm_gu256(
    const u16* __restrict__ A, const u16* __restrict__ Bg, const u16* __restrict__ Bu,
    u16* __restrict__ C, int ldc, int K, int nx) {
    extern __shared__ u16 dyn[];
    const int tid = threadIdx.x;
    const int lane = tid & 63, wid = tid >> 6;
    const int lrow = lane & 15, lg = lane >> 4;
    const int wm = wid >> 2, wn = wid & 3;

    const int orig = blockIdx.x;
    const int wg = (orig & 7) * ((int)gridDim.x >> 3) + (orig >> 3);
    const int m0 = (wg / nx) * 256, n0 = (wg % nx) * 64;

    const u16* ga[4]; const u16* gg; const u16* gu;
    int lA[4];
#pragma unroll
    for (int i = 0; i < 4; ++i) {
        int c = tid + 512 * i, r = c >> 3, kc = (c & 7) ^ (r & 7);
        ga[i] = A + (size_t)(m0 + r) * K + kc * 8;
        lA[i] = c * 8;
    }
    {
        int c = tid, r = c >> 3, kc = (c & 7) ^ (r & 7);
        gg = Bg + (size_t)(n0 + r) * K + kc * 8;
        gu = Bu + (size_t)(n0 + r) * K + kc * 8;
    }
    const int lG = 16384 + tid * 8, lU = 20480 + tid * 8;
    const int NT = K >> 6;

    auto stage = [&](int slot) {
        u16* s = dyn + slot * 24576;
#pragma unroll
        for (int i = 0; i < 4; ++i) { gll16(ga[i], s + lA[i]); ga[i] += 64; }
        gll16(gg, s + lG); gg += 64;
        gll16(gu, s + lU); gu += 64;
    };

    stage(0);
    stage(1);

    const int rowAb = (wm * 128 + lrow) * 64;
    const int rowGb = 16384 + (wn * 16 + lrow) * 64;
    const int rowUb = 20480 + (wn * 16 + lrow) * 64;
    const int cOff = (lg ^ (lrow & 7)) * 8;

    f32x4 accg[8] = {};
    f32x4 accu[8] = {};
    int slot = 0;
    for (int t = 0; t < NT; ++t) {
        if (t + 1 < NT) asm volatile("s_waitcnt vmcnt(6)" ::: "memory");
        else            asm volatile("s_waitcnt vmcnt(0)" ::: "memory");
        __builtin_amdgcn_s_barrier();
        __builtin_amdgcn_sched_barrier(0);
        if (t + 2 < NT) stage(slot == 0 ? 2 : slot - 1);

        const u16* sb = dyn + slot * 24576;
        short8 gf[2], uf[2];
        gf[0] = *(const short8*)(sb + rowGb + cOff);
        gf[1] = *(const short8*)(sb + rowGb + (cOff ^ 32));
        uf[0] = *(const short8*)(sb + rowUb + cOff);
        uf[1] = *(const short8*)(sb + rowUb + (cOff ^ 32));
#pragma unroll
        for (int p = 0; p < 4; ++p) {
            short8 af[2][2];
#pragma unroll
            for (int m = 0; m < 2; ++m) {
                af[m][0] = *(const short8*)(sb + rowAb + (2 * p + m) * 1024 + cOff);
                af[m][1] = *(const short8*)(sb + rowAb + (2 * p + m) * 1024 + (cOff ^ 32));
            }
            __builtin_amdgcn_s_setprio(1);
#pragma unroll
            for (int m = 0; m < 2; ++m) {
                accg[2 * p + m] = __builtin_amdgcn_mfma_f32_16x16x32_bf16(af[m][0], gf[0], accg[2 * p + m], 0, 0, 0);
                accg[2 * p + m] = __builtin_amdgcn_mfma_f32_16x16x32_bf16(af[m][1], gf[1], accg[2 * p + m], 0, 0, 0);
                accu[2 * p + m] = __builtin_amdgcn_mfma_f32_16x16x32_bf16(af[m][0], uf[0], accu[2 * p + m], 0, 0, 0);
                accu[2 * p + m] = __builtin_amdgcn_mfma_f32_16x16x32_bf16(af[m][1], uf[1], accu[2 * p + m], 0, 0, 0);
            }
            __builtin_amdgcn_s_setprio(0);
            if (p < 3) {
                __builtin_amdgcn_sched_barrier(0);
                __builtin_amdgcn_s_barrier();
            }
        }
        slot = slot == 2 ? 0 : slot + 1;
    }

#pragma unroll
    for (int m = 0; m < 8; ++m)
#pragma unroll
        for (int j = 0; j < 4; ++j) {
            int gm = m0 + wm * 128 + m * 16 + 4 * lg + j;
            int gn = n0 + wn * 16 + lrow;
            float g = accg[m][j];
            float u = accu[m][j];
            float v = g / (1.f + __expf(-g)) * u;
            C[(size_t)gm * ldc + gn] = f2bf(v);
        }
}

// ---------------- flash attention (causal), 64-row Q tiles, 4 waves ----------------

__global__ __launch_bounds__(256) void attn_kernel(
    const u16* __restrict__ Q, const u16* __restrict__ K, const u16* __restrict__ V,
    u16* __restrict__ O, int vstride) {
    const int bh = blockIdx.x;
    const int b = bh >> 4, h = bh & 15;
    const int q0 = ((int)gridDim.y - 1 - (int)blockIdx.y) * 64;   // heavy-first
    const int tid = threadIdx.x, wid = tid >> 6, lane = tid & 63;
    const int lrow = lane & 15, lg = lane >> 4;

    __shared__ u16 Ks[64 * 128];     // byte = r*256 + 2d ^ ((r&7)<<4)
    __shared__ u16 Vt[128 * 64];     // byte = d*128 + 2k ^ ((d&7)<<4)
    __shared__ u16 Ps[4][16 * 64];   // per-wave P

    const int qrow = q0 + wid * 16;
    short8 qf[4];
    {
        const u16* Qb = Q + ((size_t)(b * SS + qrow + lrow)) * HID + h * HD;
#pragma unroll
        for (int kc = 0; kc < 4; ++kc) qf[kc] = *(const short8*)(Qb + kc * 32 + lg * 8);
    }

    const int kr = tid >> 4, kdc = (tid & 15) * 8;
    const int r4 = tid & 15, vdc = (tid >> 4) * 8;
    const u16* Kp = K + ((size_t)(b * SS + kr)) * HID + h * HD + kdc;
    const u16* Vp = V + ((size_t)(b * SS + 4 * r4)) * vstride + h * HD + vdc;

    short8 kpre[4], vpre[4];
#pragma unroll
    for (int i = 0; i < 4; ++i) kpre[i] = *(const short8*)(Kp + (size_t)(16 * i) * HID);
#pragma unroll
    for (int i = 0; i < 4; ++i) vpre[i] = *(const short8*)(Vp + (size_t)i * vstride);

    f32x4 oacc[8] = {};
    float mrun[4] = {-3e38f, -3e38f, -3e38f, -3e38f};
    float lrun[4] = {0.f, 0.f, 0.f, 0.f};

    for (int j0 = 0; j0 <= q0; j0 += 64) {
        __syncthreads();
#pragma unroll
        for (int i = 0; i < 4; ++i) {            // K: 4x b128 swizzled
            int r = kr + 16 * i;
            *(short8*)((char*)Ks + ((r * 256 + kdc * 2) ^ ((r & 7) << 4))) = kpre[i];
        }
#pragma unroll
        for (int d = 0; d < 8; ++d) {            // V: 8x b64 (k-quad pack)
            short4v p = {vpre[0][d], vpre[1][d], vpre[2][d], vpre[3][d]};
            *(short4v*)((char*)Vt + ((((vdc + d) * 128) + 8 * r4) ^ (d << 4))) = p;
        }
        __syncthreads();

        f32x4 sacc[4] = {};
        __builtin_amdgcn_s_setprio(1);
#pragma unroll
        for (int n = 0; n < 4; ++n) {
#pragma unroll
            for (int kc = 0; kc < 4; ++kc) {
                int r = n * 16 + lrow;
                short8 kf = *(const short8*)((const char*)Ks +
                            ((r * 256 + (kc * 32 + lg * 8) * 2) ^ ((r & 7) << 4)));
                sacc[n] = __builtin_amdgcn_mfma_f32_16x16x32_bf16(qf[kc], kf, sacc[n], 0, 0, 0);
            }
        }
        __builtin_amdgcn_s_setprio(0);

        const bool diag = (j0 == q0);
        float pm[4] = {-3e38f, -3e38f, -3e38f, -3e38f};
#pragma unroll
        for (int n = 0; n < 4; ++n)
#pragma unroll
            for (int j = 0; j < 4; ++j) {
                float sv = sacc[n][j];
                if (diag && (n * 16 + lrow > wid * 16 + 4 * lg + j)) sv = -1e30f;
                sacc[n][j] = sv;
                pm[j] = fmaxf(pm[j], sv);
            }

        // prefetch next K/V tile (latency hides under softmax+PV)
        if (j0 < q0) {
            const u16* Kn = Kp + (size_t)(j0 + 64) * HID;
            const u16* Vn = Vp + (size_t)(j0 + 64) * vstride;
#pragma unroll
            for (int i = 0; i < 4; ++i) kpre[i] = *(const short8*)(Kn + (size_t)(16 * i) * HID);
#pragma unroll
            for (int i = 0; i < 4; ++i) vpre[i] = *(const short8*)(Vn + (size_t)i * vstride);
        }

#pragma unroll
        for (int j = 0; j < 4; ++j) pm[j] = rmax16(pm[j]);

        // T13 defer-max: p bounded by 2^11.5 when deferred (f32 accum safe)
        bool ok = (pm[0] <= mrun[0] + 11.5f) && (pm[1] <= mrun[1] + 11.5f) &&
                  (pm[2] <= mrun[2] + 11.5f) && (pm[3] <= mrun[3] + 11.5f);
        if (!__all(ok)) {
            float sf[4];
#pragma unroll
            for (int j = 0; j < 4; ++j) {
                float mnew = fmaxf(mrun[j], pm[j]);
                sf[j] = exp2f(mrun[j] - mnew);
                mrun[j] = mnew;
                lrun[j] *= sf[j];
            }
#pragma unroll
            for (int n = 0; n < 8; ++n)
#pragma unroll
                for (int j = 0; j < 4; ++j) oacc[n][j] *= sf[j];
        }

        float rs[4] = {0.f, 0.f, 0.f, 0.f};
#pragma unroll
        for (int n = 0; n < 4; ++n)
#pragma unroll
            for (int j = 0; j < 4; ++j) {
                float p = exp2f(sacc[n][j] - mrun[j]);
                sacc[n][j] = p;
                rs[j] += p;
            }
#pragma unroll
        for (int j = 0; j < 4; ++j) lrun[j] += rsum16(rs[j]);

#pragma unroll
        for (int n = 0; n < 4; ++n)
#pragma unroll
            for (int j = 0; j < 4; ++j) {
                int row = 4 * lg + j, col = n * 16 + lrow;
                *(u16*)((char*)&Ps[wid][0] + ((row * 128 + col * 2) ^ ((row & 7) << 4))) =
                    f2bf(sacc[n][j]);
            }
        short8 pf[2];
#pragma unroll
        for (int ks = 0; ks < 2; ++ks)
            pf[ks] = *(const short8*)((const char*)&Ps[wid][0] +
                     ((lrow * 128 + (ks * 32 + lg * 8) * 2) ^ ((lrow & 7) << 4)));
        __builtin_amdgcn_s_setprio(1);
#pragma unroll
        for (int n = 0; n < 8; ++n) {
            int d = n * 16 + lrow;
#pragma unroll
            for (int ks = 0; ks < 2; ++ks) {
                short8 vf = *(const short8*)((const char*)Vt +
                            ((d * 128 + (ks * 32 + lg * 8) * 2) ^ ((d & 7) << 4)));
                oacc[n] = __builtin_amdgcn_mfma_f32_16x16x32_bf16(pf[ks], vf, oacc[n], 0, 0, 0);
            }
        }
        __builtin_amdgcn_s_setprio(0);
    }

#pragma unroll
    for (int n = 0; n < 8; ++n)
#pragma unroll
        for (int j = 0; j < 4; ++j) {
            int row = qrow + 4 * lg + j;
            O[((size_t)(b * SS + row)) * HID + h * HD + n * 16 + lrow] =
                f2bf(oacc[n][j] / lrun[j]);
        }
}

// ---------------- launcher ----------------

extern "C" void kernel_launch(void* const* d_in, const int* in_sizes, int n_in,
                              void* d_out, int out_size, void* d_ws, size_t ws_size,
                              hipStream_t stream) {
    const float* x    = (const float*)d_in[0];
    const float* ln1w = (const float*)d_in[1];
    const float* ln1b = (const float*)d_in[2];
    const float* ln2w = (const float*)d_in[3];
    const float* ln2b = (const float*)d_in[4];
    const float* wq   = (const float*)d_in[5];
    const float* wk   = (const float*)d_in[6];
    const float* wv   = (const float*)d_in[7];
    const float* wo   = (const float*)d_in[8];
    const float* wg   = (const float*)d_in[9];
    const float* wu   = (const float*)d_in[10];
    const float* wd   = (const float*)d_in[11];

    char* ws = (char*)d_ws;
    u16*    Wbuf = (u16*)(ws);                       // 32 MiB, reused per-GEMM
    u16*    hb   = (u16*)(ws + (32UL << 20));        // 16 MiB  LN out (bf16)
    u16*    qkvb = (u16*)(ws + (48UL << 20));        // 48 MiB  QKV bf16 [4096][6144]
    u16*    qb   = (u16*)(ws + (96UL << 20));        // 16 MiB
    u16*    kb   = (u16*)(ws + (112UL << 20));       // 16 MiB
    u16*    ob   = (u16*)(ws + (128UL << 20));       // 16 MiB
    float*  x2   = (float*)(ws + (144UL << 20));     // 32 MiB  fp32 residual stream
    float2* cs   = (float2*)(ws + (176UL << 20));    // 1 MiB   rope cos/sin
    u16*    mb   = qkvb;                             // 64 MiB alias

    trig_kernel<<<512, 256, 0, stream>>>(cs);
    ln_kernel<<<4096, 256, 0, stream>>>(x, ln1w, ln1b, hb);

    // QKV projection
    cast_f32_bf16_kernel<<<2048, 256, 0, stream>>>(wq, Wbuf, 524288);
    cast_f32_bf16_kernel<<<2048, 256, 0, stream>>>(wk, Wbuf + 4194304, 524288);
    cast_f32_bf16_kernel<<<2048, 256, 0, stream>>>(wv, Wbuf + 8388608, 524288);
    gemm256<1, 0><<<768, 512, 147456, stream>>>(hb, Wbuf, qkvb, nullptr, 6144, 2048, 48);

    // Q scale = log2(e)/sqrt(128) so softmax runs in base-2 units
    rope_kernel<<<16384, 256, 0, stream>>>(qkvb, qb, cs,
                                           0.08838834764831845f * 1.4426950408889634f);
    rope_kernel<<<16384, 256, 0, stream>>>(qkvb + 2048, kb, cs, 1.0f);
    attn_kernel<<<dim3(32, 32), 256, 0, stream>>>(qb, kb, qkvb + 4096, ob, 6144);

    // O projection + residual (fp32 out)
    cast_f32_bf16_kernel<<<2048, 256, 0, stream>>>(wo, Wbuf, 524288);
    gemm256<0, 1><<<256, 512, 147456, stream>>>(ob, Wbuf, x2, x, 2048, 2048, 16);

    ln_kernel<<<4096, 256, 0, stream>>>(x2, ln2w, ln2b, hb);

    // MLP gate/up in two 4096-column halves (SiLU fused in epilogue)
    for (int h = 0; h < 2; ++h) {
        cast_f32_bf16_kernel<<<4096, 256, 0, stream>>>(wg + (size_t)h * 8388608, Wbuf, 1048576);
        cast_f32_bf16_kernel<<<4096, 256, 0, stream>>>(wu + (size_t)h * 8388608, Wbuf + 8388608, 1048576);
        gemm_gu256<<<1024, 512, 147456, stream>>>(hb, Wbuf, Wbuf + 8388608,
                                                  mb + h * 4096, 8192, 2048, 64);
    }

    // Down projection + residual -> fp32 d_out
    cast_f32_bf16_kernel<<<8192, 256, 0, stream>>>(wd, Wbuf, 2097152);
    gemm256<0, 1><<<256, 512, 147456, stream>>>(mb, Wbuf, (float*)d_out, x2, 2048, 8192, 16);
}

// Round 10
// 778.156 us; speedup vs baseline: 1.0657x; 1.0657x over previous
//
#include <hip/hip_runtime.h>
#include <hip/hip_bf16.h>

#define HID 2048
#define NH 16
#define HD 128
#define INTER 8192
#define SS 2048

typedef unsigned short u16;
typedef __attribute__((ext_vector_type(8))) short short8;
typedef __attribute__((ext_vector_type(4))) short short4v;
typedef __attribute__((ext_vector_type(4))) float f32x4;

__device__ __forceinline__ float bf2f(u16 u) {
    unsigned v = ((unsigned)u) << 16; float f; __builtin_memcpy(&f, &v, 4); return f;
}
__device__ __forceinline__ u16 f2bf(float f) {
    unsigned u; __builtin_memcpy(&u, &f, 4);
    u = u + 0x7FFFu + ((u >> 16) & 1u);   // RNE
    return (u16)(u >> 16);
}

typedef const __attribute__((address_space(1))) void* gas_t;
typedef __attribute__((address_space(3))) void* las_t;
__device__ __forceinline__ void gll16(const void* g, void* l) {
    __builtin_amdgcn_global_load_lds((gas_t)g, (las_t)l, 16, 0, 0);
}

// VALU-pipe cross-lane via DPP (16-lane-row butterfly).
template <int CTRL>
__device__ __forceinline__ float dppf(float x) {
    union { float f; int i; } u; u.f = x;
    u.i = __builtin_amdgcn_update_dpp(u.i, u.i, CTRL, 0xf, 0xf, false);
    return u.f;
}
__device__ __forceinline__ float rmax16(float x) {
    x = fmaxf(x, dppf<0xB1>(x));
    x = fmaxf(x, dppf<0x4E>(x));
    x = fmaxf(x, dppf<0x141>(x));
    x = fmaxf(x, dppf<0x140>(x));
    return x;
}
__device__ __forceinline__ float rsum16(float x) {
    x = x + dppf<0xB1>(x);
    x = x + dppf<0x4E>(x);
    x = x + dppf<0x141>(x);
    x = x + dppf<0x140>(x);
    return x;
}

// ---------------- elementwise / prep kernels ----------------

__global__ __launch_bounds__(256) void cast_f32_bf16_kernel(
    const float* __restrict__ src, u16* __restrict__ dst, int n8) {
    int gid = blockIdx.x * 256 + threadIdx.x;
    if (gid >= n8) return;
    const float4* s = (const float4*)src + (size_t)gid * 2;
    float4 a = s[0], b = s[1];
    short8 o;
    o[0] = (short)f2bf(a.x); o[1] = (short)f2bf(a.y); o[2] = (short)f2bf(a.z); o[3] = (short)f2bf(a.w);
    o[4] = (short)f2bf(b.x); o[5] = (short)f2bf(b.y); o[6] = (short)f2bf(b.z); o[7] = (short)f2bf(b.w);
    *((short8*)dst + gid) = o;
}

__global__ __launch_bounds__(256) void trig_kernel(float2* __restrict__ cs) {
    int id = blockIdx.x * 256 + threadIdx.x;   // < 2048*64
    int s = id >> 6, d = id & 63;
    float freq = expf(-(float)(2 * d) * (1.0f / (float)HD) * 9.210340371976184f); // ln(10000)
    float ang = (float)s * freq;
    cs[id] = make_float2(cosf(ang), sinf(ang));
}

__global__ __launch_bounds__(256) void ln_kernel(
    const float* __restrict__ X, const float* __restrict__ W, const float* __restrict__ Bv,
    u16* __restrict__ out) {
    const int row = blockIdx.x, tid = threadIdx.x;
    const float* xr = X + (size_t)row * HID;
    float4 v0 = ((const float4*)xr)[tid * 2];
    float4 v1 = ((const float4*)xr)[tid * 2 + 1];
    float e[8] = {v0.x, v0.y, v0.z, v0.w, v1.x, v1.y, v1.z, v1.w};
    float s = 0.f, ss2 = 0.f;
#pragma unroll
    for (int i = 0; i < 8; ++i) { s += e[i]; ss2 += e[i] * e[i]; }
#pragma unroll
    for (int m = 1; m < 64; m <<= 1) { s += __shfl_xor(s, m, 64); ss2 += __shfl_xor(ss2, m, 64); }
    __shared__ float red[8];
    if ((tid & 63) == 0) { red[tid >> 6] = s; red[4 + (tid >> 6)] = ss2; }
    __syncthreads();
    s = red[0] + red[1] + red[2] + red[3];
    ss2 = red[4] + red[5] + red[6] + red[7];
    float mean = s * (1.0f / HID);
    float var = ss2 * (1.0f / HID) - mean * mean;
    float rstd = rsqrtf(var + 1e-5f);
    float4 w0 = ((const float4*)W)[tid * 2], w1 = ((const float4*)W)[tid * 2 + 1];
    float4 b0 = ((const float4*)Bv)[tid * 2], b1 = ((const float4*)Bv)[tid * 2 + 1];
    float wv[8] = {w0.x, w0.y, w0.z, w0.w, w1.x, w1.y, w1.z, w1.w};
    float bv[8] = {b0.x, b0.y, b0.z, b0.w, b1.x, b1.y, b1.z, b1.w};
    short8 o;
#pragma unroll
    for (int i = 0; i < 8; ++i) o[i] = (short)f2bf((e[i] - mean) * rstd * wv[i] + bv[i]);
    *((short8*)(out + (size_t)row * HID) + tid) = o;
}

// RoPE on bf16 input (row stride 6144) with output pre-scale (Q gets log2e/sqrt(D))
__global__ __launch_bounds__(256) void rope_kernel(
    const u16* __restrict__ src, u16* __restrict__ dst, const float2* __restrict__ cs,
    float oscale) {
    int gid = blockIdx.x * 256 + threadIdx.x;   // < 4096*16*64
    int d = gid & 63;
    int rh = gid >> 6;
    int h = rh & (NH - 1);
    int row = rh >> 4;               // b*2048+s
    int s = row & (SS - 1);
    unsigned pair = *(const unsigned*)(src + (size_t)row * 6144 + h * HD + 2 * d);
    float x1 = bf2f((u16)(pair & 0xFFFFu));
    float x2 = bf2f((u16)(pair >> 16));
    float2 t = cs[s * 64 + d];
    u16* q = dst + (size_t)row * HID + h * HD;
    q[d] = f2bf((x1 * t.x - x2 * t.y) * oscale);
    q[64 + d] = f2bf((x1 * t.y + x2 * t.x) * oscale);
}

// ---------------- GEMM 256x128 (r8 form): 3-slot counted-vmcnt, 2 coarse phases ----------------
template <int OUT_BF16, int RESID>
__global__ __launch_bounds__(512, 2) void gemm256(
    const u16* __restrict__ A, const u16* __restrict__ B,
    void* __restrict__ C, const float* __restrict__ resid,
    int ldc, int K, int nx) {
    extern __shared__ u16 dyn[];    // 3 slots x (A 256x64 + B 128x64) u16
    const int tid = threadIdx.x;
    const int lane = tid & 63, wid = tid >> 6;
    const int lrow = lane & 15, lg = lane >> 4;
    const int wm = wid >> 2, wn = wid & 3;

    const int orig = blockIdx.x;
    const int wg = (orig & 7) * ((int)gridDim.x >> 3) + (orig >> 3);
    const int bx = wg % nx, by = wg / nx;
    const int m0 = by * 256, n0 = bx * 128;

    const u16* ga[4]; const u16* gb[2];
    int lA[4], lB[2];
#pragma unroll
    for (int i = 0; i < 4; ++i) {
        int c = tid + 512 * i, r = c >> 3, kc = (c & 7) ^ (r & 7);
        ga[i] = A + (size_t)(m0 + r) * K + kc * 8;
        lA[i] = c * 8;
    }
#pragma unroll
    for (int i = 0; i < 2; ++i) {
        int c = tid + 512 * i, r = c >> 3, kc = (c & 7) ^ (r & 7);
        gb[i] = B + (size_t)(n0 + r) * K + kc * 8;
        lB[i] = 16384 + c * 8;
    }
    const int NT = K >> 6;

    auto stage = [&](int slot) {
        u16* s = dyn + slot * 24576;
#pragma unroll
        for (int i = 0; i < 4; ++i) { gll16(ga[i], s + lA[i]); ga[i] += 64; }
#pragma unroll
        for (int i = 0; i < 2; ++i) { gll16(gb[i], s + lB[i]); gb[i] += 64; }
    };

    stage(0);
    stage(1);

    const int rowAb = (wm * 128 + lrow) * 64;
    const int rowBb = 16384 + (wn * 32 + lrow) * 64;
    const int cOff = (lg ^ (lrow & 7)) * 8;

    f32x4 acc[8][2] = {};
    int slot = 0;
    for (int t = 0; t < NT; ++t) {
        if (t + 1 < NT) asm volatile("s_waitcnt vmcnt(6)" ::: "memory");
        else            asm volatile("s_waitcnt vmcnt(0)" ::: "memory");
        __builtin_amdgcn_s_barrier();
        __builtin_amdgcn_sched_barrier(0);
        if (t + 2 < NT) stage(slot == 0 ? 2 : slot - 1);

        const u16* sb = dyn + slot * 24576;
        short8 af[4][2], bf[2][2];
#pragma unroll
        for (int m = 0; m < 4; ++m) {
            af[m][0] = *(const short8*)(sb + rowAb + m * 1024 + cOff);
            af[m][1] = *(const short8*)(sb + rowAb + m * 1024 + (cOff ^ 32));
        }
#pragma unroll
        for (int n = 0; n < 2; ++n) {
            bf[n][0] = *(const short8*)(sb + rowBb + n * 1024 + cOff);
            bf[n][1] = *(const short8*)(sb + rowBb + n * 1024 + (cOff ^ 32));
        }
        __builtin_amdgcn_s_setprio(1);
#pragma unroll
        for (int m = 0; m < 4; ++m)
#pragma unroll
            for (int n = 0; n < 2; ++n) {
                acc[m][n] = __builtin_amdgcn_mfma_f32_16x16x32_bf16(af[m][0], bf[n][0], acc[m][n], 0, 0, 0);
                acc[m][n] = __builtin_amdgcn_mfma_f32_16x16x32_bf16(af[m][1], bf[n][1], acc[m][n], 0, 0, 0);
            }
        __builtin_amdgcn_s_setprio(0);
#pragma unroll
        for (int m = 0; m < 4; ++m) {
            af[m][0] = *(const short8*)(sb + rowAb + (m + 4) * 1024 + cOff);
            af[m][1] = *(const short8*)(sb + rowAb + (m + 4) * 1024 + (cOff ^ 32));
        }
        __builtin_amdgcn_s_setprio(1);
#pragma unroll
        for (int m = 0; m < 4; ++m)
#pragma unroll
            for (int n = 0; n < 2; ++n) {
                acc[m + 4][n] = __builtin_amdgcn_mfma_f32_16x16x32_bf16(af[m][0], bf[n][0], acc[m + 4][n], 0, 0, 0);
                acc[m + 4][n] = __builtin_amdgcn_mfma_f32_16x16x32_bf16(af[m][1], bf[n][1], acc[m + 4][n], 0, 0, 0);
            }
        __builtin_amdgcn_s_setprio(0);
        slot = slot == 2 ? 0 : slot + 1;
    }

#pragma unroll
    for (int m = 0; m < 8; ++m)
#pragma unroll
        for (int n = 0; n < 2; ++n)
#pragma unroll
            for (int j = 0; j < 4; ++j) {
                int gm = m0 + wm * 128 + m * 16 + 4 * lg + j;
                int gn = n0 + wn * 32 + n * 16 + lrow;
                float v = acc[m][n][j];
                if (RESID) v += resid[(size_t)gm * ldc + gn];
                if (OUT_BF16) ((u16*)C)[(size_t)gm * ldc + gn] = f2bf(v);
                else ((float*)C)[(size_t)gm * ldc + gn] = v;
            }
}

// ---------------- GEMM 256x256: wave=128x64 (384 B LDS/MFMA), 2-slot dbuf ----------------
// Race-free 2-barrier schedule per tile:
//   barrier (compute t-1 done; its reads were consumed in-wave) ; stage(t+1) ;
//   vmcnt(8|0) (tile t's 8 oldest landed; t+1's stay in flight) ; barrier ; compute t
template <int OUT_BF16, int RESID>
__global__ __launch_bounds__(512, 2) void gemm256sq(
    const u16* __restrict__ A, const u16* __restrict__ B,
    void* __restrict__ C, const float* __restrict__ resid,
    int ldc, int K, int nx) {
    extern __shared__ u16 dyn[];    // 2 slots x (A 256x64 + B 256x64) = 128 KiB
    const int tid = threadIdx.x;
    const int lane = tid & 63, wid = tid >> 6;
    const int lrow = lane & 15, lg = lane >> 4;
    const int wm = wid >> 2, wn = wid & 3;

    const int orig = blockIdx.x;
    const int wg = (orig & 7) * ((int)gridDim.x >> 3) + (orig >> 3);
    const int m0 = (wg / nx) * 256, n0 = (wg % nx) * 256;

    const u16* ga[4]; const u16* gb[4];
    int lA[4], lB[4];
#pragma unroll
    for (int i = 0; i < 4; ++i) {
        int c = tid + 512 * i, r = c >> 3, kc = (c & 7) ^ (r & 7);
        ga[i] = A + (size_t)(m0 + r) * K + kc * 8;
        lA[i] = c * 8;
        gb[i] = B + (size_t)(n0 + r) * K + kc * 8;
        lB[i] = 16384 + c * 8;
    }
    const int NT = K >> 6;

    auto stage = [&](int slot) {
        u16* s = dyn + slot * 32768;
#pragma unroll
        for (int i = 0; i < 4; ++i) { gll16(ga[i], s + lA[i]); ga[i] += 64; }
#pragma unroll
        for (int i = 0; i < 4; ++i) { gll16(gb[i], s + lB[i]); gb[i] += 64; }
    };

    stage(0);

    const int rowAb = (wm * 128 + lrow) * 64;
    const int rowBb = 16384 + (wn * 64 + lrow) * 64;
    const int cOff = (lg ^ (lrow & 7)) * 8;

    f32x4 acc[8][4] = {};
    int slot = 0;
    for (int t = 0; t < NT; ++t) {
        __builtin_amdgcn_s_barrier();           // compute(t-1) done in all waves
        __builtin_amdgcn_sched_barrier(0);
        if (t + 1 < NT) {
            stage(slot ^ 1);
            asm volatile("s_waitcnt vmcnt(8)" ::: "memory");
        } else {
            asm volatile("s_waitcnt vmcnt(0)" ::: "memory");
        }
        __builtin_amdgcn_s_barrier();           // all waves' tile-t loads landed
        __builtin_amdgcn_sched_barrier(0);

        const u16* sb = dyn + slot * 32768;
        short8 bf[4][2];
#pragma unroll
        for (int n = 0; n < 4; ++n) {
            bf[n][0] = *(const short8*)(sb + rowBb + n * 1024 + cOff);
            bf[n][1] = *(const short8*)(sb + rowBb + n * 1024 + (cOff ^ 32));
        }
#pragma unroll
        for (int half = 0; half < 2; ++half) {
            short8 af[4][2];
#pragma unroll
            for (int m = 0; m < 4; ++m) {
                af[m][0] = *(const short8*)(sb + rowAb + (half * 4 + m) * 1024 + cOff);
                af[m][1] = *(const short8*)(sb + rowAb + (half * 4 + m) * 1024 + (cOff ^ 32));
            }
            __builtin_amdgcn_s_setprio(1);
#pragma unroll
            for (int m = 0; m < 4; ++m)
#pragma unroll
                for (int n = 0; n < 4; ++n) {
                    acc[half * 4 + m][n] = __builtin_amdgcn_mfma_f32_16x16x32_bf16(af[m][0], bf[n][0], acc[half * 4 + m][n], 0, 0, 0);
                    acc[half * 4 + m][n] = __builtin_amdgcn_mfma_f32_16x16x32_bf16(af[m][1], bf[n][1], acc[half * 4 + m][n], 0, 0, 0);
                }
            __builtin_amdgcn_s_setprio(0);
        }
        slot ^= 1;
    }

#pragma unroll
    for (int m = 0; m < 8; ++m)
#pragma unroll
        for (int n = 0; n < 4; ++n)
#pragma unroll
            for (int j = 0; j < 4; ++j) {
                int gm = m0 + wm * 128 + m * 16 + 4 * lg + j;
                int gn = n0 + wn * 64 + n * 16 + lrow;
                float v = acc[m][n][j];
                if (RESID) v += resid[(size_t)gm * ldc + gn];
                if (OUT_BF16) ((u16*)C)[(size_t)gm * ldc + gn] = f2bf(v);
                else ((float*)C)[(size_t)gm * ldc + gn] = v;
            }
}

// ---- gate/up GEMM + SiLU, 256x(128|128): waves 0-3 gate, 4-7 up; A staged once ----
// Same 2-slot schedule as gemm256sq. B slot rows 0-127 = gate cols, 128-255 = up cols.
// Epilogue: up accs -> LDS [col][row] (stride 264 f32), gate waves combine + store.
__global__ __launch_bounds__(512, 2) void gemm_gu256sq(
    const u16* __restrict__ A, const u16* __restrict__ Bg, const u16* __restrict__ Bu,
    u16* __restrict__ C, int ldc, int K, int nx) {
    extern __shared__ u16 dyn[];    // K-loop: 2x32768 u16; epilogue: 128*264 f32
    const int tid = threadIdx.x;
    const int lane = tid & 63, wid = tid >> 6;
    const int lrow = lane & 15, lg = lane >> 4;
    const int w2 = wid & 3;
    const int wmg = w2 >> 1, wng = w2 & 1, bsel = wid >> 2;

    const int orig = blockIdx.x;
    const int wg = (orig & 7) * ((int)gridDim.x >> 3) + (orig >> 3);
    const int m0 = (wg / nx) * 256, n0 = (wg % nx) * 128;

    const u16* ga[4]; const u16* gb[4];
    int lA[4], lB[4];
#pragma unroll
    for (int i = 0; i < 4; ++i) {
        int c = tid + 512 * i, r = c >> 3, kc = (c & 7) ^ (r & 7);
        ga[i] = A + (size_t)(m0 + r) * K + kc * 8;
        lA[i] = c * 8;
        gb[i] = (r < 128 ? Bg + (size_t)(n0 + r) * K : Bu + (size_t)(n0 + r - 128) * K) + kc * 8;
        lB[i] = 16384 + c * 8;
    }
    const int NT = K >> 6;

    auto stage = [&](int slot) {
        u16* s = dyn + slot * 32768;
#pragma unroll
        for (int i = 0; i < 4; ++i) { gll16(ga[i], s + lA[i]); ga[i] += 64; }
#pragma unroll
        for (int i = 0; i < 4; ++i) { gll16(gb[i], s + lB[i]); gb[i] += 64; }
    };

    stage(0);

    const int rowAb = (wmg * 128 + lrow) * 64;
    const int rowBb = 16384 + (bsel * 128 + wng * 64 + lrow) * 64;
    const int cOff = (lg ^ (lrow & 7)) * 8;

    f32x4 acc[8][4] = {};
    int slot = 0;
    for (int t = 0; t < NT; ++t) {
        __builtin_amdgcn_s_barrier();
        __builtin_amdgcn_sched_barrier(0);
        if (t + 1 < NT) {
            stage(slot ^ 1);
            asm volatile("s_waitcnt vmcnt(8)" ::: "memory");
        } else {
            asm volatile("s_waitcnt vmcnt(0)" ::: "memory");
        }
        __builtin_amdgcn_s_barrier();
        __builtin_amdgcn_sched_barrier(0);

        const u16* sb = dyn + slot * 32768;
        short8 bf[4][2];
#pragma unroll
        for (int n = 0; n < 4; ++n) {
            bf[n][0] = *(const short8*)(sb + rowBb + n * 1024 + cOff);
            bf[n][1] = *(const short8*)(sb + rowBb + n * 1024 + (cOff ^ 32));
        }
#pragma unroll
        for (int half = 0; half < 2; ++half) {
            short8 af[4][2];
#pragma unroll
            for (int m = 0; m < 4; ++m) {
                af[m][0] = *(const short8*)(sb + rowAb + (half * 4 + m) * 1024 + cOff);
                af[m][1] = *(const short8*)(sb + rowAb + (half * 4 + m) * 1024 + (cOff ^ 32));
            }
            __builtin_amdgcn_s_setprio(1);
#pragma unroll
            for (int m = 0; m < 4; ++m)
#pragma unroll
                for (int n = 0; n < 4; ++n) {
                    acc[half * 4 + m][n] = __builtin_amdgcn_mfma_f32_16x16x32_bf16(af[m][0], bf[n][0], acc[half * 4 + m][n], 0, 0, 0);
                    acc[half * 4 + m][n] = __builtin_amdgcn_mfma_f32_16x16x32_bf16(af[m][1], bf[n][1], acc[half * 4 + m][n], 0, 0, 0);
                }
            __builtin_amdgcn_s_setprio(0);
        }
        slot ^= 1;
    }

    // epilogue: up waves publish accs via LDS [col][row] (stride 264 f32)
    __syncthreads();
    float* F = (float*)dyn;
    if (bsel == 1) {
#pragma unroll
        for (int m = 0; m < 8; ++m)
#pragma unroll
            for (int n = 0; n < 4; ++n) {
                int Cl = wng * 64 + n * 16 + lrow;
                int Rl = wmg * 128 + m * 16 + 4 * lg;
                *(f32x4*)(F + Cl * 264 + Rl) = acc[m][n];
            }
    }
    __syncthreads();
    if (bsel == 0) {
#pragma unroll
        for (int m = 0; m < 8; ++m)
#pragma unroll
            for (int n = 0; n < 4; ++n) {
                int Cl = wng * 64 + n * 16 + lrow;
                int Rl = wmg * 128 + m * 16 + 4 * lg;
                f32x4 uv = *(const f32x4*)(F + Cl * 264 + Rl);
#pragma unroll
                for (int j = 0; j < 4; ++j) {
                    float g = acc[m][n][j];
                    float v = g / (1.f + __expf(-g)) * uv[j];
                    C[(size_t)(m0 + Rl + j) * ldc + (n0 + Cl)] = f2bf(v);
                }
            }
    }
}

// ---------------- flash attention (causal), 64-row Q tiles, 4 waves ----------------

__global__ __launch_bounds__(256) void attn_kernel(
    const u16* __restrict__ Q, const u16* __restrict__ K, const u16* __restrict__ V,
    u16* __restrict__ O, int vstride) {
    const int bh = blockIdx.x;
    const int b = bh >> 4, h = bh & 15;
    const int q0 = ((int)gridDim.y - 1 - (int)blockIdx.y) * 64;   // heavy-first
    const int tid = threadIdx.x, wid = tid >> 6, lane = tid & 63;
    const int lrow = lane & 15, lg = lane >> 4;

    __shared__ u16 Ks[64 * 128];     // byte = r*256 + 2d ^ ((r&7)<<4)
    __shared__ u16 Vt[128 * 64];     // byte = d*128 + 2k ^ ((d&7)<<4)
    __shared__ u16 Ps[4][16 * 64];   // per-wave P

    const int qrow = q0 + wid * 16;
    short8 qf[4];
    {
        const u16* Qb = Q + ((size_t)(b * SS + qrow + lrow)) * HID + h * HD;
#pragma unroll
        for (int kc = 0; kc < 4; ++kc) qf[kc] = *(const short8*)(Qb + kc * 32 + lg * 8);
    }

    const int kr = tid >> 4, kdc = (tid & 15) * 8;
    const int r4 = tid & 15, vdc = (tid >> 4) * 8;
    const u16* Kp = K + ((size_t)(b * SS + kr)) * HID + h * HD + kdc;
    const u16* Vp = V + ((size_t)(b * SS + 4 * r4)) * vstride + h * HD + vdc;

    short8 kpre[4], vpre[4];
#pragma unroll
    for (int i = 0; i < 4; ++i) kpre[i] = *(const short8*)(Kp + (size_t)(16 * i) * HID);
#pragma unroll
    for (int i = 0; i < 4; ++i) vpre[i] = *(const short8*)(Vp + (size_t)i * vstride);

    f32x4 oacc[8] = {};
    float mrun[4] = {-3e38f, -3e38f, -3e38f, -3e38f};
    float lrun[4] = {0.f, 0.f, 0.f, 0.f};

    for (int j0 = 0; j0 <= q0; j0 += 64) {
        __syncthreads();
#pragma unroll
        for (int i = 0; i < 4; ++i) {            // K: 4x b128 swizzled
            int r = kr + 16 * i;
            *(short8*)((char*)Ks + ((r * 256 + kdc * 2) ^ ((r & 7) << 4))) = kpre[i];
        }
#pragma unroll
        for (int d = 0; d < 8; ++d) {            // V: 8x b64 (k-quad pack)
            short4v p = {vpre[0][d], vpre[1][d], vpre[2][d], vpre[3][d]};
            *(short4v*)((char*)Vt + ((((vdc + d) * 128) + 8 * r4) ^ (d << 4))) = p;
        }
        __syncthreads();

        f32x4 sacc[4] = {};
        __builtin_amdgcn_s_setprio(1);
#pragma unroll
        for (int n = 0; n < 4; ++n) {
#pragma unroll
            for (int kc = 0; kc < 4; ++kc) {
                int r = n * 16 + lrow;
                short8 kf = *(const short8*)((const char*)Ks +
                            ((r * 256 + (kc * 32 + lg * 8) * 2) ^ ((r & 7) << 4)));
                sacc[n] = __builtin_amdgcn_mfma_f32_16x16x32_bf16(qf[kc], kf, sacc[n], 0, 0, 0);
            }
        }
        __builtin_amdgcn_s_setprio(0);

        const bool diag = (j0 == q0);
        float pm[4] = {-3e38f, -3e38f, -3e38f, -3e38f};
#pragma unroll
        for (int n = 0; n < 4; ++n)
#pragma unroll
            for (int j = 0; j < 4; ++j) {
                float sv = sacc[n][j];
                if (diag && (n * 16 + lrow > wid * 16 + 4 * lg + j)) sv = -1e30f;
                sacc[n][j] = sv;
                pm[j] = fmaxf(pm[j], sv);
            }

        // prefetch next K/V tile (latency hides under softmax+PV)
        if (j0 < q0) {
            const u16* Kn = Kp + (size_t)(j0 + 64) * HID;
            const u16* Vn = Vp + (size_t)(j0 + 64) * vstride;
#pragma unroll
            for (int i = 0; i < 4; ++i) kpre[i] = *(const short8*)(Kn + (size_t)(16 * i) * HID);
#pragma unroll
            for (int i = 0; i < 4; ++i) vpre[i] = *(const short8*)(Vn + (size_t)i * vstride);
        }

#pragma unroll
        for (int j = 0; j < 4; ++j) pm[j] = rmax16(pm[j]);

        // T13 defer-max: p bounded by 2^11.5 when deferred (f32 accum safe)
        bool ok = (pm[0] <= mrun[0] + 11.5f) && (pm[1] <= mrun[1] + 11.5f) &&
                  (pm[2] <= mrun[2] + 11.5f) && (pm[3] <= mrun[3] + 11.5f);
        if (!__all(ok)) {
            float sf[4];
#pragma unroll
            for (int j = 0; j < 4; ++j) {
                float mnew = fmaxf(mrun[j], pm[j]);
                sf[j] = exp2f(mrun[j] - mnew);
                mrun[j] = mnew;
                lrun[j] *= sf[j];
            }
#pragma unroll
            for (int n = 0; n < 8; ++n)
#pragma unroll
                for (int j = 0; j < 4; ++j) oacc[n][j] *= sf[j];
        }

        float rs[4] = {0.f, 0.f, 0.f, 0.f};
#pragma unroll
        for (int n = 0; n < 4; ++n)
#pragma unroll
            for (int j = 0; j < 4; ++j) {
                float p = exp2f(sacc[n][j] - mrun[j]);
                sacc[n][j] = p;
                rs[j] += p;
            }
#pragma unroll
        for (int j = 0; j < 4; ++j) lrun[j] += rsum16(rs[j]);

#pragma unroll
        for (int n = 0; n < 4; ++n)
#pragma unroll
            for (int j = 0; j < 4; ++j) {
                int row = 4 * lg + j, col = n * 16 + lrow;
                *(u16*)((char*)&Ps[wid][0] + ((row * 128 + col * 2) ^ ((row & 7) << 4))) =
                    f2bf(sacc[n][j]);
            }
        short8 pf[2];
#pragma unroll
        for (int ks = 0; ks < 2; ++ks)
            pf[ks] = *(const short8*)((const char*)&Ps[wid][0] +
                     ((lrow * 128 + (ks * 32 + lg * 8) * 2) ^ ((lrow & 7) << 4)));
        __builtin_amdgcn_s_setprio(1);
#pragma unroll
        for (int n = 0; n < 8; ++n) {
            int d = n * 16 + lrow;
#pragma unroll
            for (int ks = 0; ks < 2; ++ks) {
                short8 vf = *(const short8*)((const char*)Vt +
                            ((d * 128 + (ks * 32 + lg * 8) * 2) ^ ((d & 7) << 4)));
                oacc[n] = __builtin_amdgcn_mfma_f32_16x16x32_bf16(pf[ks], vf, oacc[n], 0, 0, 0);
            }
        }
        __builtin_amdgcn_s_setprio(0);
    }

#pragma unroll
    for (int n = 0; n < 8; ++n)
#pragma unroll
        for (int j = 0; j < 4; ++j) {
            int row = qrow + 4 * lg + j;
            O[((size_t)(b * SS + row)) * HID + h * HD + n * 16 + lrow] =
                f2bf(oacc[n][j] / lrun[j]);
        }
}

// ---------------- launcher ----------------

extern "C" void kernel_launch(void* const* d_in, const int* in_sizes, int n_in,
                              void* d_out, int out_size, void* d_ws, size_t ws_size,
                              hipStream_t stream) {
    const float* x    = (const float*)d_in[0];
    const float* ln1w = (const float*)d_in[1];
    const float* ln1b = (const float*)d_in[2];
    const float* ln2w = (const float*)d_in[3];
    const float* ln2b = (const float*)d_in[4];
    const float* wq   = (const float*)d_in[5];
    const float* wk   = (const float*)d_in[6];
    const float* wv   = (const float*)d_in[7];
    const float* wo   = (const float*)d_in[8];
    const float* wg   = (const float*)d_in[9];
    const float* wu   = (const float*)d_in[10];
    const float* wd   = (const float*)d_in[11];

    char* ws = (char*)d_ws;
    u16*    Wbuf = (u16*)(ws);                       // 32 MiB, reused per-GEMM
    u16*    hb   = (u16*)(ws + (32UL << 20));        // 16 MiB  LN out (bf16)
    u16*    qkvb = (u16*)(ws + (48UL << 20));        // 48 MiB  QKV bf16 [4096][6144]
    u16*    qb   = (u16*)(ws + (96UL << 20));        // 16 MiB
    u16*    kb   = (u16*)(ws + (112UL << 20));       // 16 MiB
    u16*    ob   = (u16*)(ws + (128UL << 20));       // 16 MiB
    float*  x2   = (float*)(ws + (144UL << 20));     // 32 MiB  fp32 residual stream
    float2* cs   = (float2*)(ws + (176UL << 20));    // 1 MiB   rope cos/sin
    u16*    mb   = qkvb;                             // 64 MiB alias

    trig_kernel<<<512, 256, 0, stream>>>(cs);
    ln_kernel<<<4096, 256, 0, stream>>>(x, ln1w, ln1b, hb);

    // QKV projection (256x256 kernel: grid 16x24 = 384)
    cast_f32_bf16_kernel<<<2048, 256, 0, stream>>>(wq, Wbuf, 524288);
    cast_f32_bf16_kernel<<<2048, 256, 0, stream>>>(wk, Wbuf + 4194304, 524288);
    cast_f32_bf16_kernel<<<2048, 256, 0, stream>>>(wv, Wbuf + 8388608, 524288);
    gemm256sq<1, 0><<<384, 512, 131072, stream>>>(hb, Wbuf, qkvb, nullptr, 6144, 2048, 24);

    // Q scale = log2(e)/sqrt(128) so softmax runs in base-2 units
    rope_kernel<<<16384, 256, 0, stream>>>(qkvb, qb, cs,
                                           0.08838834764831845f * 1.4426950408889634f);
    rope_kernel<<<16384, 256, 0, stream>>>(qkvb + 2048, kb, cs, 1.0f);
    attn_kernel<<<dim3(32, 32), 256, 0, stream>>>(qb, kb, qkvb + 4096, ob, 6144);

    // O projection + residual (fp32 out)
    cast_f32_bf16_kernel<<<2048, 256, 0, stream>>>(wo, Wbuf, 524288);
    gemm256<0, 1><<<256, 512, 147456, stream>>>(ob, Wbuf, x2, x, 2048, 2048, 16);

    ln_kernel<<<4096, 256, 0, stream>>>(x2, ln2w, ln2b, hb);

    // MLP gate/up in two 4096-column halves (grid 16x32 = 512 each)
    for (int h = 0; h < 2; ++h) {
        cast_f32_bf16_kernel<<<4096, 256, 0, stream>>>(wg + (size_t)h * 8388608, Wbuf, 1048576);
        cast_f32_bf16_kernel<<<4096, 256, 0, stream>>>(wu + (size_t)h * 8388608, Wbuf + 8388608, 1048576);
        gemm_gu256sq<<<512, 512, 135168, stream>>>(hb, Wbuf, Wbuf + 8388608,
                                                   mb + h * 4096, 8192, 2048, 32);
    }

    // Down projection + residual -> fp32 d_out
    cast_f32_bf16_kernel<<<8192, 256, 0, stream>>>(wd, Wbuf, 2097152);
    gemm256<0, 1><<<256, 512, 147456, stream>>>(mb, Wbuf, (float*)d_out, x2, 2048, 8192, 16);
}